// Round 1
// baseline (499.182 us; speedup 1.0000x reference)
//
#include <hip/hip_runtime.h>
#include <math.h>

#define BLK 256

__global__ __launch_bounds__(BLK, 2)
void pose_kernel(const float* __restrict__ rots,
                 const float* __restrict__ jtrs,
                 const float* __restrict__ W0,
                 const float* __restrict__ b0,
                 const float* __restrict__ W1,
                 const float* __restrict__ b1,
                 const float* __restrict__ W2,
                 const float* __restrict__ b2,
                 float* __restrict__ out,
                 int bsz)
{
    constexpr int PAR[24] = {-1,0,0,0,1,2,3,4,5,6,7,8,9,9,9,12,13,14,16,17,18,19,20,21};
    int b = blockIdx.x * BLK + threadIdx.x;
    if (b >= bsz) return;

    const float* rr = rots + (size_t)b * 216;   // 864B row, 16B aligned
    const float* jr = jtrs + (size_t)b * 72;    // 288B row, 16B aligned
    float* orow = out + (size_t)b * 144;        // 576B row, 16B aligned

    // ---- Jtrs row into registers (needed for bone lengths + x[9..11]) ----
    float jt[72];
    {
        const float4* p4 = reinterpret_cast<const float4*>(jr);
        #pragma unroll
        for (int i = 0; i < 18; ++i) {
            float4 v = p4[i];
            jt[4*i+0] = v.x; jt[4*i+1] = v.y; jt[4*i+2] = v.z; jt[4*i+3] = v.w;
        }
    }

    // ---- gfeat = [rots_row(216), jtrs_row(72)] @ W0^T + b0 ----
    float gf[6];
    #pragma unroll
    for (int d = 0; d < 6; ++d) gf[d] = b0[d];

    {
        const float4* p4 = reinterpret_cast<const float4*>(rr);
        #pragma unroll
        for (int i = 0; i < 54; ++i) {
            float4 v = p4[i];
            #pragma unroll
            for (int d = 0; d < 6; ++d) {
                const float* w = W0 + d*288 + 4*i;   // uniform -> s_load
                gf[d] = fmaf(v.x, w[0], gf[d]);
                gf[d] = fmaf(v.y, w[1], gf[d]);
                gf[d] = fmaf(v.z, w[2], gf[d]);
                gf[d] = fmaf(v.w, w[3], gf[d]);
            }
        }
    }
    #pragma unroll
    for (int i = 0; i < 72; ++i) {
        #pragma unroll
        for (int d = 0; d < 6; ++d)
            gf[d] = fmaf(jt[i], W0[d*288 + 216 + i], gf[d]);
    }

    // ---- sequential joint chain, fully unrolled (PAR[j] compile-time) ----
    float outv[24][6];

    #pragma unroll
    for (int j = 0; j < 24; ++j) {
        const int p = PAR[j];
        float x[19];
        // rot re-read: L3-resident (226MB total footprint < 256MB LLC)
        #pragma unroll
        for (int k = 0; k < 9; ++k) x[k] = rr[j*9 + k];
        const float jx = jt[j*3+0], jy = jt[j*3+1], jz = jt[j*3+2];
        x[9] = jx; x[10] = jy; x[11] = jz;
        float dx, dy, dz;
        if (p < 0) { dx = jx; dy = jy; dz = jz; }
        else {
            dx = jx - jt[p*3+0];
            dy = jy - jt[p*3+1];
            dz = jz - jt[p*3+2];
        }
        x[12] = sqrtf(dx*dx + dy*dy + dz*dz);
        #pragma unroll
        for (int d = 0; d < 6; ++d) x[13+d] = (p < 0) ? gf[d] : outv[p][d];

        float h[19];
        #pragma unroll
        for (int r = 0; r < 19; ++r) {
            float acc = b1[j*19 + r];
            const float* w = W1 + (j*19 + r)*19;     // uniform -> s_load
            #pragma unroll
            for (int c = 0; c < 19; ++c) acc = fmaf(x[c], w[c], acc);
            h[r] = fmaxf(acc, 0.0f);
        }
        #pragma unroll
        for (int d = 0; d < 6; ++d) {
            float acc = b2[j*6 + d];
            const float* w = W2 + (j*6 + d)*19;      // uniform -> s_load
            #pragma unroll
            for (int r = 0; r < 19; ++r) acc = fmaf(h[r], w[r], acc);
            outv[j][d] = acc;
        }
        // 3x float2 stores (8B aligned: b*576 + j*24 + d*4, d even)
        #pragma unroll
        for (int d = 0; d < 6; d += 2) {
            float2 v; v.x = outv[j][d]; v.y = outv[j][d+1];
            *reinterpret_cast<float2*>(orow + j*6 + d) = v;
        }
    }
}

extern "C" void kernel_launch(void* const* d_in, const int* in_sizes, int n_in,
                              void* d_out, int out_size, void* d_ws, size_t ws_size,
                              hipStream_t stream)
{
    const float* rots = (const float*)d_in[0];
    const float* jtrs = (const float*)d_in[1];
    const float* W0   = (const float*)d_in[2];
    const float* b0   = (const float*)d_in[3];
    const float* W1   = (const float*)d_in[4];
    const float* b1   = (const float*)d_in[5];
    const float* W2   = (const float*)d_in[6];
    const float* b2   = (const float*)d_in[7];
    float* out = (float*)d_out;

    int bsz = in_sizes[0] / 216;
    int blocks = (bsz + BLK - 1) / BLK;
    hipLaunchKernelGGL(pose_kernel, dim3(blocks), dim3(BLK), 0, stream,
                       rots, jtrs, W0, b0, W1, b1, W2, b2, out, bsz);
}

// Round 2
// 466.376 us; speedup vs baseline: 1.0703x; 1.0703x over previous
//
#include <hip/hip_runtime.h>
#include <math.h>

#define BLK 512  // 128 rows/block, 4 lanes per row

constexpr int PAR_CT[24] = {-1,0,0,0,1,2,3,4,5,6,7,8,9,9,9,12,13,14,16,17,18,19,20,21};

// load 3 consecutive floats starting at element E from a float4* base (E compile-time)
template<int E>
__device__ __forceinline__ void load3(const float4* __restrict__ p, float& a, float& b, float& c) {
    constexpr int q = E / 4, s = E % 4;
    float4 v0 = p[q];
    if constexpr (s == 0)      { a = v0.x; b = v0.y; c = v0.z; }
    else if constexpr (s == 1) { a = v0.y; b = v0.z; c = v0.w; }
    else if constexpr (s == 2) { float4 v1 = p[q+1]; a = v0.z; b = v0.w; c = v1.x; }
    else                       { float4 v1 = p[q+1]; a = v0.w; b = v1.x; c = v1.y; }
}

template<int J>
__device__ __forceinline__ void joint_step(const float4* __restrict__ rp,
                                           const float4* __restrict__ jp,
                                           const float* __restrict__ W1s,
                                           const float* __restrict__ W2s,
                                           const float* __restrict__ b2,
                                           const float (&gf)[6],
                                           float (&o)[24][6],
                                           float* __restrict__ orow,
                                           int l)
{
    constexpr int P = PAR_CT[J];

    // ---- jt triple for this joint (+ parent) : compile-time f4 windows ----
    float jx, jy, jz;
    load3<3*J>(jp, jx, jy, jz);
    float dx, dy, dz;
    if constexpr (P < 0) { dx = jx; dy = jy; dz = jz; }
    else {
        float px, py, pz;
        load3<3*P>(jp, px, py, pz);
        dx = jx - px; dy = jy - py; dz = jz - pz;
    }
    const float bl = sqrtf(dx*dx + dy*dy + dz*dz);

    // ---- rot[9J .. 9J+8] via 3 aligned float4 loads (L1/L2 resident) ----
    constexpr int w0  = (9*J) / 4;
    constexpr int off = (9*J) % 4;
    float4 A = rp[w0], B = rp[w0+1], C = rp[w0+2];
    float rv[12] = {A.x,A.y,A.z,A.w, B.x,B.y,B.z,B.w, C.x,C.y,C.z,C.w};

    // ---- feat (replicated in all 4 lanes) ----
    float f0,f1,f2,f3,f4v,f5;
    if constexpr (P < 0) { f0=gf[0]; f1=gf[1]; f2=gf[2]; f3=gf[3]; f4v=gf[4]; f5=gf[5]; }
    else { f0=o[P][0]; f1=o[P][1]; f2=o[P][2]; f3=o[P][3]; f4v=o[P][4]; f5=o[P][5]; }

    // ---- layer 1: rows r = l + 4u (5 for l<3, 4 for l==3), x replicated ----
    float h[5];
    #pragma unroll
    for (int u = 0; u < 5; ++u) {
        const int r = l + 4*u;
        if (r < 19) {
            const float* w = W1s + J*380 + r*20;   // row-padded to 20, slot19 = b1
            float4 wa = *(const float4*)(w);
            float4 wb = *(const float4*)(w + 4);
            float4 wc = *(const float4*)(w + 8);
            float4 wd = *(const float4*)(w + 12);
            float4 we = *(const float4*)(w + 16);
            float acc = we.w;                      // b1[j][r]
            acc = fmaf(rv[off+0], wa.x, acc);
            acc = fmaf(rv[off+1], wa.y, acc);
            acc = fmaf(rv[off+2], wa.z, acc);
            acc = fmaf(rv[off+3], wa.w, acc);
            acc = fmaf(rv[off+4], wb.x, acc);
            acc = fmaf(rv[off+5], wb.y, acc);
            acc = fmaf(rv[off+6], wb.z, acc);
            acc = fmaf(rv[off+7], wb.w, acc);
            acc = fmaf(rv[off+8], wc.x, acc);
            acc = fmaf(jx, wc.y, acc);
            acc = fmaf(jy, wc.z, acc);
            acc = fmaf(jz, wc.w, acc);
            acc = fmaf(bl, wd.x, acc);
            acc = fmaf(f0, wd.y, acc);
            acc = fmaf(f1, wd.z, acc);
            acc = fmaf(f2, wd.w, acc);
            acc = fmaf(f3, we.x, acc);
            acc = fmaf(f4v, we.y, acc);
            acc = fmaf(f5, we.z, acc);
            h[u] = fmaxf(acc, 0.0f);
        }
    }

    // ---- layer 2: partial over owned rows, W2s = [j][r][6] transposed ----
    float od[6] = {0,0,0,0,0,0};
    #pragma unroll
    for (int u = 0; u < 5; ++u) {
        const int r = l + 4*u;
        if (r < 19) {
            const float* w = W2s + J*114 + r*6;
            float2 wa = *(const float2*)(w);
            float2 wb = *(const float2*)(w + 2);
            float2 wc = *(const float2*)(w + 4);
            od[0] = fmaf(h[u], wa.x, od[0]);
            od[1] = fmaf(h[u], wa.y, od[1]);
            od[2] = fmaf(h[u], wb.x, od[2]);
            od[3] = fmaf(h[u], wb.y, od[3]);
            od[4] = fmaf(h[u], wc.x, od[4]);
            od[5] = fmaf(h[u], wc.y, od[5]);
        }
    }

    // ---- reduce across the 4-lane group; add bias; all lanes get full o ----
    #pragma unroll
    for (int d = 0; d < 6; ++d) {
        od[d] += __shfl_xor(od[d], 1, 4);
        od[d] += __shfl_xor(od[d], 2, 4);
        od[d] += b2[J*6 + d];                      // uniform -> s_load
        o[J][d] = od[d];
    }

    // ---- store 6 floats: lanes 0..2 write one float2 each ----
    float s0 = (l == 0) ? od[0] : (l == 1) ? od[2] : od[4];
    float s1 = (l == 0) ? od[1] : (l == 1) ? od[3] : od[5];
    if (l < 3) {
        float2 v; v.x = s0; v.y = s1;
        *reinterpret_cast<float2*>(orow + J*6 + 2*l) = v;
    }
}

template<int J>
__device__ __forceinline__ void run_chain(const float4* __restrict__ rp,
                                          const float4* __restrict__ jp,
                                          const float* __restrict__ W1s,
                                          const float* __restrict__ W2s,
                                          const float* __restrict__ b2,
                                          const float (&gf)[6],
                                          float (&o)[24][6],
                                          float* __restrict__ orow,
                                          int l)
{
    if constexpr (J < 24) {
        joint_step<J>(rp, jp, W1s, W2s, b2, gf, o, orow, l);
        run_chain<J+1>(rp, jp, W1s, W2s, b2, gf, o, orow, l);
    }
}

__global__ __launch_bounds__(BLK, 6)
void pose_kernel(const float* __restrict__ rots,
                 const float* __restrict__ jtrs,
                 const float* __restrict__ W0,
                 const float* __restrict__ b0,
                 const float* __restrict__ W1,
                 const float* __restrict__ b1,
                 const float* __restrict__ W2,
                 const float* __restrict__ b2,
                 float* __restrict__ out,
                 int bsz)
{
    __shared__ __align__(16) float W1s[24*19*20];  // 36.48 KB, [j][r][20], slot19=b1
    __shared__ __align__(16) float W2s[24*19*6];   // 10.94 KB, [j][r][d]

    for (int idx = threadIdx.x; idx < 24*19*20; idx += BLK) {
        int j = idx / 380, rem = idx % 380, r = rem / 20, c = rem % 20;
        W1s[idx] = (c < 19) ? W1[(j*19 + r)*19 + c] : b1[j*19 + r];
    }
    for (int idx = threadIdx.x; idx < 24*19*6; idx += BLK) {
        int j = idx / 114, rem = idx % 114, r = rem / 6, d = rem % 6;
        W2s[idx] = W2[(j*6 + d)*19 + r];           // transpose: [j][r][d]
    }
    __syncthreads();

    const int t   = blockIdx.x * BLK + threadIdx.x;
    const int row = t >> 2;
    const int l   = t & 3;
    if (row >= bsz) return;

    const float4* rp = reinterpret_cast<const float4*>(rots + (size_t)row * 216); // 54 f4
    const float4* jp = reinterpret_cast<const float4*>(jtrs + (size_t)row * 72);  // 18 f4
    float* orow = out + (size_t)row * 144;

    // ---- gfeat: lane l owns f4 indices m = 4i+l -> each group reads full 64B lines ----
    float gf[6] = {0,0,0,0,0,0};
    #pragma unroll
    for (int i = 0; i < 14; ++i) {
        const int m = 4*i + l;
        if (m < 54) {
            float4 v = rp[m];
            #pragma unroll
            for (int d = 0; d < 6; ++d) {
                float4 w = *reinterpret_cast<const float4*>(W0 + d*288 + 4*m);
                gf[d] = fmaf(v.x, w.x, gf[d]);
                gf[d] = fmaf(v.y, w.y, gf[d]);
                gf[d] = fmaf(v.z, w.z, gf[d]);
                gf[d] = fmaf(v.w, w.w, gf[d]);
            }
        }
    }
    #pragma unroll
    for (int i = 0; i < 5; ++i) {
        const int m = 4*i + l;
        if (m < 18) {
            float4 v = jp[m];
            #pragma unroll
            for (int d = 0; d < 6; ++d) {
                float4 w = *reinterpret_cast<const float4*>(W0 + d*288 + 216 + 4*m);
                gf[d] = fmaf(v.x, w.x, gf[d]);
                gf[d] = fmaf(v.y, w.y, gf[d]);
                gf[d] = fmaf(v.z, w.z, gf[d]);
                gf[d] = fmaf(v.w, w.w, gf[d]);
            }
        }
    }
    #pragma unroll
    for (int d = 0; d < 6; ++d) {
        gf[d] += __shfl_xor(gf[d], 1, 4);
        gf[d] += __shfl_xor(gf[d], 2, 4);
        gf[d] += b0[d];
    }

    // ---- sequential 24-joint chain ----
    float o[24][6];
    run_chain<0>(rp, jp, W1s, W2s, b2, gf, o, orow, l);
}

extern "C" void kernel_launch(void* const* d_in, const int* in_sizes, int n_in,
                              void* d_out, int out_size, void* d_ws, size_t ws_size,
                              hipStream_t stream)
{
    const float* rots = (const float*)d_in[0];
    const float* jtrs = (const float*)d_in[1];
    const float* W0   = (const float*)d_in[2];
    const float* b0   = (const float*)d_in[3];
    const float* W1   = (const float*)d_in[4];
    const float* b1   = (const float*)d_in[5];
    const float* W2   = (const float*)d_in[6];
    const float* b2   = (const float*)d_in[7];
    float* out = (float*)d_out;

    int bsz = in_sizes[0] / 216;
    long long threads = (long long)bsz * 4;
    int blocks = (int)((threads + BLK - 1) / BLK);
    hipLaunchKernelGGL(pose_kernel, dim3(blocks), dim3(BLK), 0, stream,
                       rots, jtrs, W0, b0, W1, b1, W2, b2, out, bsz);
}

// Round 3
// 342.256 us; speedup vs baseline: 1.4585x; 1.3627x over previous
//
#include <hip/hip_runtime.h>
#include <math.h>

#define BLK 256  // 64 rows/block, 4 lanes per row

constexpr int PAR_CT[24] = {-1,0,0,0,1,2,3,4,5,6,7,8,9,9,9,12,13,14,16,17,18,19,20,21};

// broadcast staged float4 #M (owned by lane M&3, reg M>>2) to all 4 lanes of the quad
template<int M>
__device__ __forceinline__ float4 bcast_f4(const float4 (&s)[14]) {
    constexpr int lane = M & 3, reg = M >> 2;
    float4 v = s[reg], r;
    r.x = __shfl(v.x, lane, 4);
    r.y = __shfl(v.y, lane, 4);
    r.z = __shfl(v.z, lane, 4);
    r.w = __shfl(v.w, lane, 4);
    return r;
}

// broadcast jtr element #E from the 5-f4 stage (f4 m=E/4 owned by lane m&3, reg m>>2)
template<int E>
__device__ __forceinline__ float bcast_jt(const float4 (&s)[5]) {
    constexpr int m = E >> 2, lane = m & 3, reg = m >> 2, c = E & 3;
    float4 v = s[reg];
    float x = (c == 0) ? v.x : (c == 1) ? v.y : (c == 2) ? v.z : v.w;
    return __shfl(x, lane, 4);
}

template<int J>
__device__ __forceinline__ void joint_step(const float4 (&rot_s)[14],
                                           const float4 (&jt_s)[5],
                                           const float* __restrict__ W1s,
                                           const float* __restrict__ W2s,
                                           const float* __restrict__ b2,
                                           const float (&gf)[6],
                                           float (&o)[24][6],
                                           float* __restrict__ orow,
                                           int l)
{
    constexpr int P = PAR_CT[J];

    // ---- jtr triples via quad broadcast (DPP, no memory) ----
    const float jx = bcast_jt<3*J+0>(jt_s);
    const float jy = bcast_jt<3*J+1>(jt_s);
    const float jz = bcast_jt<3*J+2>(jt_s);
    float dx, dy, dz;
    if constexpr (P < 0) { dx = jx; dy = jy; dz = jz; }
    else {
        const float px = bcast_jt<3*P+0>(jt_s);
        const float py = bcast_jt<3*P+1>(jt_s);
        const float pz = bcast_jt<3*P+2>(jt_s);
        dx = jx - px; dy = jy - py; dz = jz - pz;
    }
    const float bl = sqrtf(dx*dx + dy*dy + dz*dz);

    // ---- rot[9J..9J+8] via 3 quad-broadcast f4s (registers, no memory) ----
    constexpr int w0  = (9*J) / 4;
    constexpr int off = (9*J) % 4;
    float4 A = bcast_f4<w0  >(rot_s);
    float4 B = bcast_f4<w0+1>(rot_s);
    float4 C = bcast_f4<w0+2>(rot_s);
    float rv[12] = {A.x,A.y,A.z,A.w, B.x,B.y,B.z,B.w, C.x,C.y,C.z,C.w};

    // ---- feat (replicated in all 4 lanes) ----
    float f0,f1,f2,f3,f4v,f5;
    if constexpr (P < 0) { f0=gf[0]; f1=gf[1]; f2=gf[2]; f3=gf[3]; f4v=gf[4]; f5=gf[5]; }
    else { f0=o[P][0]; f1=o[P][1]; f2=o[P][2]; f3=o[P][3]; f4v=o[P][4]; f5=o[P][5]; }

    // ---- layer 1: rows r = l + 4u, weights from LDS (4-addr + broadcast, no conflicts) ----
    float h[5];
    #pragma unroll
    for (int u = 0; u < 5; ++u) {
        const int r = l + 4*u;
        if (r < 19) {
            const float* w = W1s + J*380 + r*20;   // [j][r][20], slot19 = b1
            float4 wa = *(const float4*)(w);
            float4 wb = *(const float4*)(w + 4);
            float4 wc = *(const float4*)(w + 8);
            float4 wd = *(const float4*)(w + 12);
            float4 we = *(const float4*)(w + 16);
            float acc = we.w;                      // b1[j][r]
            acc = fmaf(rv[off+0], wa.x, acc);
            acc = fmaf(rv[off+1], wa.y, acc);
            acc = fmaf(rv[off+2], wa.z, acc);
            acc = fmaf(rv[off+3], wa.w, acc);
            acc = fmaf(rv[off+4], wb.x, acc);
            acc = fmaf(rv[off+5], wb.y, acc);
            acc = fmaf(rv[off+6], wb.z, acc);
            acc = fmaf(rv[off+7], wb.w, acc);
            acc = fmaf(rv[off+8], wc.x, acc);
            acc = fmaf(jx, wc.y, acc);
            acc = fmaf(jy, wc.z, acc);
            acc = fmaf(jz, wc.w, acc);
            acc = fmaf(bl, wd.x, acc);
            acc = fmaf(f0, wd.y, acc);
            acc = fmaf(f1, wd.z, acc);
            acc = fmaf(f2, wd.w, acc);
            acc = fmaf(f3, we.x, acc);
            acc = fmaf(f4v, we.y, acc);
            acc = fmaf(f5, we.z, acc);
            h[u] = fmaxf(acc, 0.0f);
        }
    }

    // ---- layer 2: W2s = [j][r][8] (pad), 2x b128 per row ----
    float od[6] = {0,0,0,0,0,0};
    #pragma unroll
    for (int u = 0; u < 5; ++u) {
        const int r = l + 4*u;
        if (r < 19) {
            const float* w = W2s + J*152 + r*8;
            float4 wa = *(const float4*)(w);
            float4 wb = *(const float4*)(w + 4);
            od[0] = fmaf(h[u], wa.x, od[0]);
            od[1] = fmaf(h[u], wa.y, od[1]);
            od[2] = fmaf(h[u], wa.z, od[2]);
            od[3] = fmaf(h[u], wa.w, od[3]);
            od[4] = fmaf(h[u], wb.x, od[4]);
            od[5] = fmaf(h[u], wb.y, od[5]);
        }
    }

    // ---- reduce across quad; add bias; all lanes get full o[J] ----
    #pragma unroll
    for (int d = 0; d < 6; ++d) {
        od[d] += __shfl_xor(od[d], 1, 4);
        od[d] += __shfl_xor(od[d], 2, 4);
        od[d] += b2[J*6 + d];                      // uniform -> s_load
        o[J][d] = od[d];
    }

    // ---- paired store: at odd J write o[J-1] (still live) + o[J] as 3x float4 ----
    if constexpr (J & 1) {
        if (l < 3) {
            float4 v;
            if (l == 0)      { v.x = o[J-1][0]; v.y = o[J-1][1]; v.z = o[J-1][2]; v.w = o[J-1][3]; }
            else if (l == 1) { v.x = o[J-1][4]; v.y = o[J-1][5]; v.z = o[J][0];   v.w = o[J][1];   }
            else             { v.x = o[J][2];   v.y = o[J][3];   v.z = o[J][4];   v.w = o[J][5];   }
            *reinterpret_cast<float4*>(orow + (J-1)*6 + 4*l) = v;  // 16B-aligned
        }
    }
}

template<int J>
__device__ __forceinline__ void run_chain(const float4 (&rot_s)[14],
                                          const float4 (&jt_s)[5],
                                          const float* __restrict__ W1s,
                                          const float* __restrict__ W2s,
                                          const float* __restrict__ b2,
                                          const float (&gf)[6],
                                          float (&o)[24][6],
                                          float* __restrict__ orow,
                                          int l)
{
    if constexpr (J < 24) {
        joint_step<J>(rot_s, jt_s, W1s, W2s, b2, gf, o, orow, l);
        run_chain<J+1>(rot_s, jt_s, W1s, W2s, b2, gf, o, orow, l);
    }
}

__global__ __launch_bounds__(BLK, 3)
void pose_kernel(const float* __restrict__ rots,
                 const float* __restrict__ jtrs,
                 const float* __restrict__ W0,
                 const float* __restrict__ b0,
                 const float* __restrict__ W1,
                 const float* __restrict__ b1,
                 const float* __restrict__ W2,
                 const float* __restrict__ b2,
                 float* __restrict__ out,
                 int bsz)
{
    __shared__ __align__(16) float W1s[24*19*20];  // 36.48 KB, [j][r][20], slot19=b1
    __shared__ __align__(16) float W2s[24*19*8];   // 14.59 KB, [j][r][8], pad 6,7

    for (int idx = threadIdx.x; idx < 24*19*20; idx += BLK) {
        int j = idx / 380, rem = idx % 380, r = rem / 20, c = rem % 20;
        W1s[idx] = (c < 19) ? W1[(j*19 + r)*19 + c] : b1[j*19 + r];
    }
    for (int idx = threadIdx.x; idx < 24*19*8; idx += BLK) {
        int j = idx / 152, rem = idx % 152, r = rem / 8, d = rem % 8;
        W2s[idx] = (d < 6) ? W2[(j*6 + d)*19 + r] : 0.0f;   // transpose: [j][r][d]
    }
    __syncthreads();

    const int t   = blockIdx.x * BLK + threadIdx.x;
    const int row = t >> 2;
    const int l   = t & 3;
    if (row >= bsz) return;

    const float4* rp = reinterpret_cast<const float4*>(rots + (size_t)row * 216); // 54 f4
    const float4* jp = reinterpret_cast<const float4*>(jtrs + (size_t)row * 72);  // 18 f4
    float* orow = out + (size_t)row * 144;

    // ---- stage the whole row ONCE, coalesced (lane l owns f4 m=4i+l) ----
    float4 rot_s[14];
    #pragma unroll
    for (int i = 0; i < 13; ++i) rot_s[i] = rp[4*i + l];
    if (l < 2) rot_s[13] = rp[52 + l];                 // m=52,53 only

    float4 jt_s[5];
    #pragma unroll
    for (int i = 0; i < 4; ++i) jt_s[i] = jp[4*i + l];
    if (l < 2) jt_s[4] = jp[16 + l];                   // m=16,17 only

    // ---- gfeat from staged registers (zero global re-reads of the row) ----
    float gf[6] = {0,0,0,0,0,0};
    #pragma unroll
    for (int i = 0; i < 13; ++i) {
        const int m = 4*i + l;
        float4 v = rot_s[i];
        #pragma unroll
        for (int d = 0; d < 6; ++d) {
            float4 w = *reinterpret_cast<const float4*>(W0 + d*288 + 4*m);
            gf[d] = fmaf(v.x, w.x, gf[d]);
            gf[d] = fmaf(v.y, w.y, gf[d]);
            gf[d] = fmaf(v.z, w.z, gf[d]);
            gf[d] = fmaf(v.w, w.w, gf[d]);
        }
    }
    if (l < 2) {
        const int m = 52 + l;
        float4 v = rot_s[13];
        #pragma unroll
        for (int d = 0; d < 6; ++d) {
            float4 w = *reinterpret_cast<const float4*>(W0 + d*288 + 4*m);
            gf[d] = fmaf(v.x, w.x, gf[d]);
            gf[d] = fmaf(v.y, w.y, gf[d]);
            gf[d] = fmaf(v.z, w.z, gf[d]);
            gf[d] = fmaf(v.w, w.w, gf[d]);
        }
    }
    #pragma unroll
    for (int i = 0; i < 4; ++i) {
        const int m = 4*i + l;
        float4 v = jt_s[i];
        #pragma unroll
        for (int d = 0; d < 6; ++d) {
            float4 w = *reinterpret_cast<const float4*>(W0 + d*288 + 216 + 4*m);
            gf[d] = fmaf(v.x, w.x, gf[d]);
            gf[d] = fmaf(v.y, w.y, gf[d]);
            gf[d] = fmaf(v.z, w.z, gf[d]);
            gf[d] = fmaf(v.w, w.w, gf[d]);
        }
    }
    if (l < 2) {
        const int m = 16 + l;
        float4 v = jt_s[4];
        #pragma unroll
        for (int d = 0; d < 6; ++d) {
            float4 w = *reinterpret_cast<const float4*>(W0 + d*288 + 216 + 4*m);
            gf[d] = fmaf(v.x, w.x, gf[d]);
            gf[d] = fmaf(v.y, w.y, gf[d]);
            gf[d] = fmaf(v.z, w.z, gf[d]);
            gf[d] = fmaf(v.w, w.w, gf[d]);
        }
    }
    #pragma unroll
    for (int d = 0; d < 6; ++d) {
        gf[d] += __shfl_xor(gf[d], 1, 4);
        gf[d] += __shfl_xor(gf[d], 2, 4);
        gf[d] += b0[d];
    }

    // ---- sequential 24-joint chain (registers + LDS + DPP only) ----
    float o[24][6];
    run_chain<0>(rot_s, jt_s, W1s, W2s, b2, gf, o, orow, l);
}

extern "C" void kernel_launch(void* const* d_in, const int* in_sizes, int n_in,
                              void* d_out, int out_size, void* d_ws, size_t ws_size,
                              hipStream_t stream)
{
    const float* rots = (const float*)d_in[0];
    const float* jtrs = (const float*)d_in[1];
    const float* W0   = (const float*)d_in[2];
    const float* b0   = (const float*)d_in[3];
    const float* W1   = (const float*)d_in[4];
    const float* b1   = (const float*)d_in[5];
    const float* W2   = (const float*)d_in[6];
    const float* b2   = (const float*)d_in[7];
    float* out = (float*)d_out;

    int bsz = in_sizes[0] / 216;
    long long threads = (long long)bsz * 4;
    int blocks = (int)((threads + BLK - 1) / BLK);
    hipLaunchKernelGGL(pose_kernel, dim3(blocks), dim3(BLK), 0, stream,
                       rots, jtrs, W0, b0, W1, b1, W2, b2, out, bsz);
}